// Round 14
// baseline (242.635 us; speedup 1.0000x reference)
//
#include <hip/hip_runtime.h>
#include <hip/hip_bf16.h>

// SimVQ: z[16,1024,64] f32, codebook[16384,64] f32, proj_w[64,64] f32, proj_b[64] f32, scale f32
// Outputs (fp32, concat): quantized_st[1048576], vq_loss[1], idx[16384]
// r28 = r27 + geometry-only parallelism fixes (no logic changes).
// r27 post-mortem: k_final 57µs @ VALU 9%/Occ 12.5% -> tail is a latency-bound serial
// chain at 2 blocks/CU (grid-limited), and was ALWAYS so (k_out had same geometry,
// hidden under top-5 cutoff). Accounting also exposed k_prep ~41µs (2 blocks/CU,
// HBM-cold z/cb, 16 serial rows/wave). Fixes: k_final 512->1024 blocks (4 tok/wave,
// 4 blocks/CU, cnt/idx prefetched); k_prep znorm 256->1024 blocks (4 rows/wave);
// g_partial->1024, fixed-order loss sum kept deterministic. GEMM passes untouched
// (49µs plateau invariant: r17/r18/r21/r26 all null).
// Margin scheme proven r5-r14: pass1 mfma top value, pass2 collect within 8e-3
// (bf16 quant err <= 4e-3 + Ozaki proj err ~1e-5), fp64 arbiter on cnt>=2 tokens.

#define NCODES 16384
#define NTOK   16384
#define DIM    64
#define MARGIN_MFMA 8e-3f
#define CAP    16

typedef __attribute__((ext_vector_type(8))) short bf16x8;
typedef __attribute__((ext_vector_type(4))) float f32x4;
#define GLOBAL_AS __attribute__((address_space(1)))
#define LDS_AS    __attribute__((address_space(3)))

__device__ float  g_qcb[NCODES * DIM];   // 4 MB projected codebook fp32 (gather source)
__device__ short  g_cnb[NCODES * DIM];   // 2 MB l2norm(qcb) bf16 row-major (MFMA B)
__device__ short  g_znb[NTOK * DIM];     // 2 MB l2norm(z)  bf16 row-major (MFMA A)
__device__ unsigned g_topu[NTOK];        // orderable-encoded mfma top-1 value
__device__ int    g_candcnt[NTOK];
__device__ int    g_cand[NTOK * CAP];    // 1 MB; slot 0 = top-1 candidate from pass 2
__device__ int    g_done;                // k_final last-block counter (zeroed in k_prep)
__device__ float  g_partial[1024];       // per-block loss partials (all written every call)

__device__ __forceinline__ float wave_sum64(float v) {
#pragma unroll
  for (int o = 32; o > 0; o >>= 1) v += __shfl_xor(v, o, 64);
  return v;
}
__device__ __forceinline__ short f2bf(float f) {
  __hip_bfloat16 h = __float2bfloat16(f);
  return *reinterpret_cast<short*>(&h);
}
__device__ __forceinline__ float bf2f(short s) {
  __hip_bfloat16 h = *reinterpret_cast<__hip_bfloat16*>(&s);
  return __bfloat162float(h);
}
__device__ __forceinline__ void split8(const float* v, bf16x8& hi, bf16x8& lo) {
#pragma unroll
  for (int i = 0; i < 8; ++i) {
    float f = v[i];
    short h = f2bf(f);
    hi[i] = h;
    lo[i] = f2bf(f - bf2f(h));
  }
}

// k_prep (r28): blocks [0,256): projection (unchanged). blocks [256,1280): znorm over
// 1024 blocks, 16 rows each, wave owns 4 rows (was 16 serial rows/wave at 256 blocks)
// -> 4x waves in flight to hide HBM latency on the cold z read. State zeroing spread
// over the 1024 znorm blocks.
__global__ __launch_bounds__(256) void k_prep(const float* __restrict__ cb,
                                              const float* __restrict__ pw,
                                              const float* __restrict__ pb,
                                              const float* __restrict__ z) {
  int tid = threadIdx.x;
  int wave = tid >> 6, lane = tid & 63, quad = lane >> 4, col = lane & 15;
  if (blockIdx.x < 256) {
    int rowBase = blockIdx.x * 64 + wave * 16;
    const float* cr = cb + (size_t)(rowBase + col) * 64 + quad * 8;
    bf16x8 ah0, al0, ah1, al1;
    split8(cr, ah0, al0);
    split8(cr + 32, ah1, al1);
    float vals[4][4];
    float nr[4] = {0.f, 0.f, 0.f, 0.f};
    const f32x4 fz = {0.f, 0.f, 0.f, 0.f};
#pragma unroll
    for (int nt = 0; nt < 4; ++nt) {
      int j = col + 16 * nt;
      const float* wr = pw + (size_t)j * 64 + quad * 8;
      bf16x8 bh0, bl0, bh1, bl1;
      split8(wr, bh0, bl0);
      split8(wr + 32, bh1, bl1);
      f32x4 d = __builtin_amdgcn_mfma_f32_16x16x32_bf16(ah0, bh0, fz, 0, 0, 0);
      d = __builtin_amdgcn_mfma_f32_16x16x32_bf16(ah1, bh1, d, 0, 0, 0);
      d = __builtin_amdgcn_mfma_f32_16x16x32_bf16(ah0, bl0, d, 0, 0, 0);
      d = __builtin_amdgcn_mfma_f32_16x16x32_bf16(ah1, bl1, d, 0, 0, 0);
      d = __builtin_amdgcn_mfma_f32_16x16x32_bf16(al0, bh0, d, 0, 0, 0);
      d = __builtin_amdgcn_mfma_f32_16x16x32_bf16(al1, bh1, d, 0, 0, 0);
      float bj = pb[j];
#pragma unroll
      for (int r = 0; r < 4; ++r) {
        float v = d[r] + bj;
        vals[nt][r] = v;
        nr[r] = fmaf(v, v, nr[r]);
      }
    }
#pragma unroll
    for (int r = 0; r < 4; ++r) {
      float v = nr[r];
      v += __shfl_xor(v, 1, 64);
      v += __shfl_xor(v, 2, 64);
      v += __shfl_xor(v, 4, 64);
      v += __shfl_xor(v, 8, 64);
      nr[r] = 1.0f / fmaxf(sqrtf(v), 1e-12f);
    }
#pragma unroll
    for (int nt = 0; nt < 4; ++nt)
#pragma unroll
      for (int r = 0; r < 4; ++r) {
        int row = rowBase + quad * 4 + r;
        int j = col + 16 * nt;
        g_qcb[(size_t)row * 64 + j] = vals[nt][r];
        g_cnb[(size_t)row * 64 + j] = f2bf(vals[nt][r] * nr[r]);
      }
  } else {
    int zb = blockIdx.x - 256;          // 0..1023
    int gid = zb * 16 + tid;            // NOTE: covers 0..16383+ for zeroing via stride
    // zero per-call state: 1024 blocks x 256 threads cover 262144 slots; guard to NTOK
    int zgid = zb * 256 + tid;
    if (zgid < NTOK) { g_topu[zgid] = 0u; g_candcnt[zgid] = 0; }
    if (zgid == 0) g_done = 0;
    (void)gid;
    int base = zb * 16;                 // 16 rows per block
    int row = base + wave * 4;          // wave owns 4 rows
#pragma unroll
    for (int r = 0; r < 4; ++r) {
      float v = z[(size_t)(row + r) * 64 + lane];
      float tot = wave_sum64(v * v);
      g_znb[(size_t)(row + r) * 64 + lane] = f2bf(v / fmaxf(sqrtf(tot), 1e-12f));
    }
  }
}

// GEMM pass 1 (r26, unchanged): grid 1024 = 64 tokGroups x 16 splits, 4 waves/block,
// wave owns 64 tokens (4 f-groups). Split = 1024 codes, 8 stages of 128 codes (16KB),
// double-buffered, global_load_lds width-16, XOR-swizzled; ONE barrier/stage.
__global__ __launch_bounds__(256) void k_mfma1() {
  __shared__ __align__(16) short smB[2][8192];
  int tid = threadIdx.x;
  int wave = tid >> 6, lane = tid & 63;
  int quad = lane >> 4, col = lane & 15;
  int tokGroup = blockIdx.x >> 4, split = blockIdx.x & 15;
  int tokBase = tokGroup * 256 + wave * 64;

  const short* za = g_znb + (size_t)(tokBase + col) * 64 + quad * 8;
  bf16x8 A0[4], A1[4];
#pragma unroll
  for (int f = 0; f < 4; ++f) {
    A0[f] = *(const bf16x8*)(za + f * 16 * 64);
    A1[f] = *(const bf16x8*)(za + f * 16 * 64 + 32);
  }
  float m[4][4];
#pragma unroll
  for (int f = 0; f < 4; ++f)
#pragma unroll
    for (int r = 0; r < 4; ++r) m[f][r] = -3.0e38f;

  const char* gsplit = (const char*)(g_cnb + (size_t)split * 1024 * 64);
  int x = col & 7;
  int s0off = ((quad ^ x) << 3);
  int s1off = (((4 | quad) ^ x) << 3);
  int goff[4];
#pragma unroll
  for (int i = 0; i < 4; ++i) {
    int cidx = wave * 256 + i * 64 + lane;
    int row = cidx >> 3, sw = cidx & 7;
    goff[i] = row * 128 + ((sw ^ (row & 7)) << 4);
  }

#pragma unroll
  for (int i = 0; i < 4; ++i)
    __builtin_amdgcn_global_load_lds((const GLOBAL_AS void*)(gsplit + goff[i]),
                                     (LDS_AS void*)(&smB[0][wave * 2048 + i * 512]), 16, 0, 0);
  __syncthreads();

  int p = 0;
  for (int s = 0; s < 8; ++s) {
    if (s < 7) {
      const char* gb = gsplit + (size_t)(s + 1) * 16384;
#pragma unroll
      for (int i = 0; i < 4; ++i)
        __builtin_amdgcn_global_load_lds((const GLOBAL_AS void*)(gb + goff[i]),
                                         (LDS_AS void*)(&smB[p ^ 1][wave * 2048 + i * 512]),
                                         16, 0, 0);
    }
    const short* bufp = smB[p];
#pragma unroll
    for (int h = 0; h < 2; ++h) {
      bf16x8 B0[4], B1[4];
#pragma unroll
      for (int t = 0; t < 4; ++t) {
        const short* lb = bufp + ((h * 4 + t) * 16 + col) * 64;
        B0[t] = *(const bf16x8*)(lb + s0off);
        B1[t] = *(const bf16x8*)(lb + s1off);
      }
#pragma unroll
      for (int t = 0; t < 4; ++t) {
#pragma unroll
        for (int f = 0; f < 4; ++f) {
          f32x4 acc = {0.f, 0.f, 0.f, 0.f};
          acc = __builtin_amdgcn_mfma_f32_16x16x32_bf16(A0[f], B0[t], acc, 0, 0, 0);
          acc = __builtin_amdgcn_mfma_f32_16x16x32_bf16(A1[f], B1[t], acc, 0, 0, 0);
#pragma unroll
          for (int r = 0; r < 4; ++r) m[f][r] = fmaxf(m[f][r], acc[r]);
        }
      }
    }
    __syncthreads();
    p ^= 1;
  }

#pragma unroll
  for (int f = 0; f < 4; ++f)
#pragma unroll
    for (int r = 0; r < 4; ++r) {
      float v = m[f][r];
      v = fmaxf(v, __shfl_xor(v, 1, 64));
      v = fmaxf(v, __shfl_xor(v, 2, 64));
      v = fmaxf(v, __shfl_xor(v, 4, 64));
      v = fmaxf(v, __shfl_xor(v, 8, 64));
      if (col == 0) {
        unsigned b = __float_as_uint(v);
        unsigned e = (b & 0x80000000u) ? ~b : (b | 0x80000000u);
        atomicMax(&g_topu[tokBase + f * 16 + quad * 4 + r], e);
      }
    }
}

// GEMM pass 2 (r26, unchanged): same 16-split/8-stage skeleton; collect candidates.
__global__ __launch_bounds__(256) void k_mfma2() {
  __shared__ __align__(16) short smB[2][8192];
  int tid = threadIdx.x;
  int wave = tid >> 6, lane = tid & 63;
  int quad = lane >> 4, col = lane & 15;
  int tokGroup = blockIdx.x >> 4, split = blockIdx.x & 15;
  int tokBase = tokGroup * 256 + wave * 64;

  const short* za = g_znb + (size_t)(tokBase + col) * 64 + quad * 8;
  bf16x8 A0[4], A1[4];
#pragma unroll
  for (int f = 0; f < 4; ++f) {
    A0[f] = *(const bf16x8*)(za + f * 16 * 64);
    A1[f] = *(const bf16x8*)(za + f * 16 * 64 + 32);
  }
  float th[4][4];
#pragma unroll
  for (int f = 0; f < 4; ++f)
#pragma unroll
    for (int r = 0; r < 4; ++r) {
      unsigned u = g_topu[tokBase + f * 16 + quad * 4 + r];
      unsigned b = (u & 0x80000000u) ? (u & 0x7FFFFFFFu) : ~u;
      th[f][r] = __uint_as_float(b) - MARGIN_MFMA;
    }

  const char* gsplit = (const char*)(g_cnb + (size_t)split * 1024 * 64);
  int x = col & 7;
  int s0off = ((quad ^ x) << 3);
  int s1off = (((4 | quad) ^ x) << 3);
  int goff[4];
#pragma unroll
  for (int i = 0; i < 4; ++i) {
    int cidx = wave * 256 + i * 64 + lane;
    int row = cidx >> 3, sw = cidx & 7;
    goff[i] = row * 128 + ((sw ^ (row & 7)) << 4);
  }

#pragma unroll
  for (int i = 0; i < 4; ++i)
    __builtin_amdgcn_global_load_lds((const GLOBAL_AS void*)(gsplit + goff[i]),
                                     (LDS_AS void*)(&smB[0][wave * 2048 + i * 512]), 16, 0, 0);
  __syncthreads();

  int codeB = split * 1024 + col;
  int p = 0;
  for (int s = 0; s < 8; ++s) {
    if (s < 7) {
      const char* gb = gsplit + (size_t)(s + 1) * 16384;
#pragma unroll
      for (int i = 0; i < 4; ++i)
        __builtin_amdgcn_global_load_lds((const GLOBAL_AS void*)(gb + goff[i]),
                                         (LDS_AS void*)(&smB[p ^ 1][wave * 2048 + i * 512]),
                                         16, 0, 0);
    }
    const short* bufp = smB[p];
#pragma unroll
    for (int h = 0; h < 2; ++h) {
      bf16x8 B0[4], B1[4];
#pragma unroll
      for (int t = 0; t < 4; ++t) {
        const short* lb = bufp + ((h * 4 + t) * 16 + col) * 64;
        B0[t] = *(const bf16x8*)(lb + s0off);
        B1[t] = *(const bf16x8*)(lb + s1off);
      }
#pragma unroll
      for (int t = 0; t < 4; ++t) {
        int code = codeB + s * 128 + (h * 4 + t) * 16;
#pragma unroll
        for (int f = 0; f < 4; ++f) {
          f32x4 acc = {0.f, 0.f, 0.f, 0.f};
          acc = __builtin_amdgcn_mfma_f32_16x16x32_bf16(A0[f], B0[t], acc, 0, 0, 0);
          acc = __builtin_amdgcn_mfma_f32_16x16x32_bf16(A1[f], B1[t], acc, 0, 0, 0);
          float dmax = fmaxf(fmaxf(acc[0] - th[f][0], acc[1] - th[f][1]),
                             fmaxf(acc[2] - th[f][2], acc[3] - th[f][3]));
          if (dmax >= 0.f) {
#pragma unroll
            for (int r = 0; r < 4; ++r) {
              if (acc[r] >= th[f][r]) {
                int tok = tokBase + f * 16 + quad * 4 + r;
                int pos = atomicAdd(&g_candcnt[tok], 1);
                if (pos < CAP) g_cand[tok * CAP + pos] = code;
              }
            }
          }
        }
      }
    }
    __syncthreads();
    p ^= 1;
  }
}

// k_final (r28): fused scan+arb+out+loss at 1024 blocks x 4 waves; wave owns 4 tokens
// (cnt/idx prefetched for ILP). Per token: cnt>=2 -> inline fp64 arbiter (verbatim);
// else winner = slot0. Gather/ST/idx/loss-partial as k_out. Loss: device-scope atomic
// partials + g_done; last block replays fixed-order sum. 4 blocks/CU (LDS 34.8KB).
__global__ __launch_bounds__(256) void k_final(const float* __restrict__ z,
                                               const float* __restrict__ cb,
                                               const float* __restrict__ pw,
                                               const float* __restrict__ pb,
                                               float* __restrict__ out0,
                                               float* __restrict__ out1,
                                               float* __restrict__ out2) {
  __shared__ double WT[64 * 65];  // WT[k*65+j] = W[j][k]
  __shared__ float cbl[4][64];
  __shared__ float ws[4];
  __shared__ int lastFlag;
  int tid = threadIdx.x;
  int wave = tid >> 6, lane = tid & 63;
  for (int e = tid; e < 4096; e += 256) {
    int j = e >> 6, k = e & 63;
    WT[k * 65 + j] = (double)pw[e];
  }
  __syncthreads();

  double bj = (double)pb[lane];
  int base = blockIdx.x * 16;
  // prefetch cnt/idx for the wave's 4 tokens (independent loads batched)
  int cnts[4], idxs[4];
#pragma unroll
  for (int r8 = 0; r8 < 4; ++r8) {
    int tok = base + wave * 4 + r8;
    cnts[r8] = g_candcnt[tok];
    idxs[r8] = g_cand[tok * CAP];
  }
  float lsum = 0.f;
#pragma unroll
  for (int r8 = 0; r8 < 4; ++r8) {
    int tok = base + wave * 4 + r8;
    int cnt = cnts[r8];
    int idx = idxs[r8];
    if (cnt >= 2) {
      double zj = (double)z[(size_t)tok * 64 + lane];
      double best = -1.0e300;
      int bi = 0x7FFFFFFF;
      int lim = (cnt <= CAP) ? cnt : 0;
      for (int c = 0; c < lim; ++c) {
        int code = g_cand[tok * CAP + c];
        cbl[wave][lane] = cb[(size_t)code * 64 + lane];
        double s0 = 0.0, s1 = 0.0, s2 = 0.0, s3 = 0.0;
#pragma unroll
        for (int kk = 0; kk < 16; ++kk) {
          s0 = fma(WT[kk * 65 + lane], (double)cbl[wave][kk], s0);
          s1 = fma(WT[(kk + 16) * 65 + lane], (double)cbl[wave][kk + 16], s1);
          s2 = fma(WT[(kk + 32) * 65 + lane], (double)cbl[wave][kk + 32], s2);
          s3 = fma(WT[(kk + 48) * 65 + lane], (double)cbl[wave][kk + 48], s3);
        }
        double qc = ((s0 + s1) + (s2 + s3)) + bj;
        double s = zj * qc, n2 = qc * qc;
#pragma unroll
        for (int o = 32; o > 0; o >>= 1) {
          s += __shfl_xor(s, o, 64);
          n2 += __shfl_xor(n2, o, 64);
        }
        double key = s / fmax(sqrt(n2), 1e-12);
        if (key > best || (key == best && code < bi)) { best = key; bi = code; }
      }
      if (cnt > CAP) {  // correctness insurance; empirically never fires
        for (int code = 0; code < NCODES; ++code) {
          cbl[wave][lane] = cb[(size_t)code * 64 + lane];
          double s0 = 0.0, s1 = 0.0, s2 = 0.0, s3 = 0.0;
#pragma unroll
          for (int kk = 0; kk < 16; ++kk) {
            s0 = fma(WT[kk * 65 + lane], (double)cbl[wave][kk], s0);
            s1 = fma(WT[(kk + 16) * 65 + lane], (double)cbl[wave][kk + 16], s1);
            s2 = fma(WT[(kk + 32) * 65 + lane], (double)cbl[wave][kk + 32], s2);
            s3 = fma(WT[(kk + 48) * 65 + lane], (double)cbl[wave][kk + 48], s3);
          }
          double qc = ((s0 + s1) + (s2 + s3)) + bj;
          double s = zj * qc, n2 = qc * qc;
#pragma unroll
          for (int o = 32; o > 0; o >>= 1) {
            s += __shfl_xor(s, o, 64);
            n2 += __shfl_xor(n2, o, 64);
          }
          double key = s / fmax(sqrt(n2), 1e-12);
          if (key > best || (key == best && code < bi)) { best = key; bi = code; }
        }
      }
      idx = bi;
    }
    float q = g_qcb[(size_t)idx * 64 + lane];
    float zv = z[(size_t)tok * 64 + lane];
    float d = q - zv;
    out0[(size_t)tok * 64 + lane] = zv + d;  // z + (q - z), ref op order
    lsum = fmaf(d, d, lsum);
    if (lane == 0) out2[tok] = (float)idx;
  }
  float tot = wave_sum64(lsum);
  if (lane == 0) ws[wave] = tot;
  __syncthreads();
  if (tid == 0) {
    float p = ((ws[0] + ws[1]) + (ws[2] + ws[3]));
    __hip_atomic_store(&g_partial[blockIdx.x], p, __ATOMIC_RELEASE,
                       __HIP_MEMORY_SCOPE_AGENT);
    int prev = __hip_atomic_fetch_add(&g_done, 1, __ATOMIC_ACQ_REL,
                                      __HIP_MEMORY_SCOPE_AGENT);
    lastFlag = (prev == 1023) ? 1 : 0;
  }
  __syncthreads();
  if (lastFlag && wave == 0) {  // last-arriving block replays fixed-order loss sum
    float s = 0.f;
#pragma unroll
    for (int i = 0; i < 16; ++i)
      s += __hip_atomic_load(&g_partial[lane + 64 * i], __ATOMIC_ACQUIRE,
                             __HIP_MEMORY_SCOPE_AGENT);
    s = wave_sum64(s);
    if (lane == 0) out1[0] = 1.25f * s / 1048576.0f;  // commitment == codebook numerically
  }
}

extern "C" void kernel_launch(void* const* d_in, const int* in_sizes, int n_in,
                              void* d_out, int out_size, void* d_ws, size_t ws_size,
                              hipStream_t stream) {
  const float* z = (const float*)d_in[0];
  const float* cb = (const float*)d_in[1];
  const float* pw = (const float*)d_in[2];
  const float* pb = (const float*)d_in[3];
  // d_in[4] (scale) unused: argmin invariant to positive scale

  float* out0 = (float*)d_out;
  float* out1 = out0 + (size_t)NTOK * DIM;
  float* out2 = out1 + 1;

  hipLaunchKernelGGL(k_prep, dim3(1280), dim3(256), 0, stream, cb, pw, pb, z);
  hipLaunchKernelGGL(k_mfma1, dim3(1024), dim3(256), 0, stream);
  hipLaunchKernelGGL(k_mfma2, dim3(1024), dim3(256), 0, stream);
  hipLaunchKernelGGL(k_final, dim3(1024), dim3(256), 0, stream, z, cb, pw, pb,
                     out0, out1, out2);
}

// Round 15
// 189.191 us; speedup vs baseline: 1.2825x; 1.2825x over previous
//
#include <hip/hip_runtime.h>
#include <hip/hip_bf16.h>

// SimVQ: z[16,1024,64] f32, codebook[16384,64] f32, proj_w[64,64] f32, proj_b[64] f32, scale f32
// Outputs (fp32, concat): quantized_st[1048576], vq_loss[1], idx[16384]
// r29 = r26 (verified 194.2µs best, separate kernels) + k_out geometry fix + r28's
// parallelized k_prep znorm (hw-verified correct). Fusion twice-refuted (r27 57µs
// neutral, r28 102µs regression via unroll bloat + per-block WT): tail cost is k_out's
// 2-blocks/CU latency-bound gather (true traffic ~12MB = ~2µs BW floor). Fix: k_out
// 512->2048 blocks (8/CU), 2 tokens/wave, idx prefetched; g_partial->2048; k_loss
// fixed-order 32/lane. k_scan/k_arb/k_mfma1/k_mfma2 byte-identical to r26 (passes at
// the proven 49µs plateau; invariant to reads/barriers/MFMA-count: r17/r18/r21/r26).
// Margin scheme proven r5-r14: pass1 mfma top value, pass2 collect within 8e-3
// (bf16 quant err <= 4e-3 + Ozaki proj err ~1e-5), fp64 arbiter on cnt>=2 tokens.

#define NCODES 16384
#define NTOK   16384
#define DIM    64
#define MARGIN_MFMA 8e-3f
#define CAP    16

typedef __attribute__((ext_vector_type(8))) short bf16x8;
typedef __attribute__((ext_vector_type(4))) float f32x4;
#define GLOBAL_AS __attribute__((address_space(1)))
#define LDS_AS    __attribute__((address_space(3)))

__device__ float  g_qcb[NCODES * DIM];   // 4 MB projected codebook fp32 (gather source)
__device__ short  g_cnb[NCODES * DIM];   // 2 MB l2norm(qcb) bf16 row-major (MFMA B)
__device__ short  g_znb[NTOK * DIM];     // 2 MB l2norm(z)  bf16 row-major (MFMA A)
__device__ unsigned g_topu[NTOK];        // orderable-encoded mfma top-1 value
__device__ int    g_candcnt[NTOK];
__device__ int    g_cand[NTOK * CAP];    // 1 MB; slot 0 holds the winner after k_arb
__device__ int    g_wl[NTOK];            // flagged-token worklist
__device__ int    g_wln;
__device__ float  g_partial[2048];       // per-block loss partials (all written every call)

__device__ __forceinline__ float wave_sum64(float v) {
#pragma unroll
  for (int o = 32; o > 0; o >>= 1) v += __shfl_xor(v, o, 64);
  return v;
}
__device__ __forceinline__ short f2bf(float f) {
  __hip_bfloat16 h = __float2bfloat16(f);
  return *reinterpret_cast<short*>(&h);
}
__device__ __forceinline__ float bf2f(short s) {
  __hip_bfloat16 h = *reinterpret_cast<__hip_bfloat16*>(&s);
  return __bfloat162float(h);
}
__device__ __forceinline__ void split8(const float* v, bf16x8& hi, bf16x8& lo) {
#pragma unroll
  for (int i = 0; i < 8; ++i) {
    float f = v[i];
    short h = f2bf(f);
    hi[i] = h;
    lo[i] = f2bf(f - bf2f(h));
  }
}

// k_prep: blocks [0,256): projection qc = cb@W^T + b via Ozaki hi/lo bf16 MFMA ->
// fp32 qcb, bf16 cnb. blocks [256,1280): znorm over 1024 blocks, 16 rows each, wave
// owns 4 rows (r28 geometry, hw-verified) + zero per-call state (g_wln for k_scan).
__global__ __launch_bounds__(256) void k_prep(const float* __restrict__ cb,
                                              const float* __restrict__ pw,
                                              const float* __restrict__ pb,
                                              const float* __restrict__ z) {
  int tid = threadIdx.x;
  int wave = tid >> 6, lane = tid & 63, quad = lane >> 4, col = lane & 15;
  if (blockIdx.x < 256) {
    int rowBase = blockIdx.x * 64 + wave * 16;
    const float* cr = cb + (size_t)(rowBase + col) * 64 + quad * 8;
    bf16x8 ah0, al0, ah1, al1;
    split8(cr, ah0, al0);
    split8(cr + 32, ah1, al1);
    float vals[4][4];
    float nr[4] = {0.f, 0.f, 0.f, 0.f};
    const f32x4 fz = {0.f, 0.f, 0.f, 0.f};
#pragma unroll
    for (int nt = 0; nt < 4; ++nt) {
      int j = col + 16 * nt;
      const float* wr = pw + (size_t)j * 64 + quad * 8;
      bf16x8 bh0, bl0, bh1, bl1;
      split8(wr, bh0, bl0);
      split8(wr + 32, bh1, bl1);
      f32x4 d = __builtin_amdgcn_mfma_f32_16x16x32_bf16(ah0, bh0, fz, 0, 0, 0);
      d = __builtin_amdgcn_mfma_f32_16x16x32_bf16(ah1, bh1, d, 0, 0, 0);
      d = __builtin_amdgcn_mfma_f32_16x16x32_bf16(ah0, bl0, d, 0, 0, 0);
      d = __builtin_amdgcn_mfma_f32_16x16x32_bf16(ah1, bl1, d, 0, 0, 0);
      d = __builtin_amdgcn_mfma_f32_16x16x32_bf16(al0, bh0, d, 0, 0, 0);
      d = __builtin_amdgcn_mfma_f32_16x16x32_bf16(al1, bh1, d, 0, 0, 0);
      float bj = pb[j];
#pragma unroll
      for (int r = 0; r < 4; ++r) {
        float v = d[r] + bj;
        vals[nt][r] = v;
        nr[r] = fmaf(v, v, nr[r]);
      }
    }
#pragma unroll
    for (int r = 0; r < 4; ++r) {
      float v = nr[r];
      v += __shfl_xor(v, 1, 64);
      v += __shfl_xor(v, 2, 64);
      v += __shfl_xor(v, 4, 64);
      v += __shfl_xor(v, 8, 64);
      nr[r] = 1.0f / fmaxf(sqrtf(v), 1e-12f);
    }
#pragma unroll
    for (int nt = 0; nt < 4; ++nt)
#pragma unroll
      for (int r = 0; r < 4; ++r) {
        int row = rowBase + quad * 4 + r;
        int j = col + 16 * nt;
        g_qcb[(size_t)row * 64 + j] = vals[nt][r];
        g_cnb[(size_t)row * 64 + j] = f2bf(vals[nt][r] * nr[r]);
      }
  } else {
    int zb = blockIdx.x - 256;          // 0..1023
    int zgid = zb * 256 + tid;
    if (zgid < NTOK) { g_topu[zgid] = 0u; g_candcnt[zgid] = 0; }
    if (zgid == 0) g_wln = 0;
    int base = zb * 16;                 // 16 rows per block
    int row = base + wave * 4;          // wave owns 4 rows
#pragma unroll
    for (int r = 0; r < 4; ++r) {
      float v = z[(size_t)(row + r) * 64 + lane];
      float tot = wave_sum64(v * v);
      g_znb[(size_t)(row + r) * 64 + lane] = f2bf(v / fmaxf(sqrtf(tot), 1e-12f));
    }
  }
}

// GEMM pass 1 (r26, unchanged): grid 1024 = 64 tokGroups x 16 splits, 4 waves/block,
// wave owns 64 tokens (4 f-groups). Split = 1024 codes, 8 stages of 128 codes (16KB),
// double-buffered, global_load_lds width-16, XOR-swizzled; ONE barrier/stage.
__global__ __launch_bounds__(256) void k_mfma1() {
  __shared__ __align__(16) short smB[2][8192];
  int tid = threadIdx.x;
  int wave = tid >> 6, lane = tid & 63;
  int quad = lane >> 4, col = lane & 15;
  int tokGroup = blockIdx.x >> 4, split = blockIdx.x & 15;
  int tokBase = tokGroup * 256 + wave * 64;

  const short* za = g_znb + (size_t)(tokBase + col) * 64 + quad * 8;
  bf16x8 A0[4], A1[4];
#pragma unroll
  for (int f = 0; f < 4; ++f) {
    A0[f] = *(const bf16x8*)(za + f * 16 * 64);
    A1[f] = *(const bf16x8*)(za + f * 16 * 64 + 32);
  }
  float m[4][4];
#pragma unroll
  for (int f = 0; f < 4; ++f)
#pragma unroll
    for (int r = 0; r < 4; ++r) m[f][r] = -3.0e38f;

  const char* gsplit = (const char*)(g_cnb + (size_t)split * 1024 * 64);
  int x = col & 7;
  int s0off = ((quad ^ x) << 3);
  int s1off = (((4 | quad) ^ x) << 3);
  int goff[4];
#pragma unroll
  for (int i = 0; i < 4; ++i) {
    int cidx = wave * 256 + i * 64 + lane;
    int row = cidx >> 3, sw = cidx & 7;
    goff[i] = row * 128 + ((sw ^ (row & 7)) << 4);
  }

#pragma unroll
  for (int i = 0; i < 4; ++i)
    __builtin_amdgcn_global_load_lds((const GLOBAL_AS void*)(gsplit + goff[i]),
                                     (LDS_AS void*)(&smB[0][wave * 2048 + i * 512]), 16, 0, 0);
  __syncthreads();

  int p = 0;
  for (int s = 0; s < 8; ++s) {
    if (s < 7) {
      const char* gb = gsplit + (size_t)(s + 1) * 16384;
#pragma unroll
      for (int i = 0; i < 4; ++i)
        __builtin_amdgcn_global_load_lds((const GLOBAL_AS void*)(gb + goff[i]),
                                         (LDS_AS void*)(&smB[p ^ 1][wave * 2048 + i * 512]),
                                         16, 0, 0);
    }
    const short* bufp = smB[p];
#pragma unroll
    for (int h = 0; h < 2; ++h) {
      bf16x8 B0[4], B1[4];
#pragma unroll
      for (int t = 0; t < 4; ++t) {
        const short* lb = bufp + ((h * 4 + t) * 16 + col) * 64;
        B0[t] = *(const bf16x8*)(lb + s0off);
        B1[t] = *(const bf16x8*)(lb + s1off);
      }
#pragma unroll
      for (int t = 0; t < 4; ++t) {
#pragma unroll
        for (int f = 0; f < 4; ++f) {
          f32x4 acc = {0.f, 0.f, 0.f, 0.f};
          acc = __builtin_amdgcn_mfma_f32_16x16x32_bf16(A0[f], B0[t], acc, 0, 0, 0);
          acc = __builtin_amdgcn_mfma_f32_16x16x32_bf16(A1[f], B1[t], acc, 0, 0, 0);
#pragma unroll
          for (int r = 0; r < 4; ++r) m[f][r] = fmaxf(m[f][r], acc[r]);
        }
      }
    }
    __syncthreads();
    p ^= 1;
  }

#pragma unroll
  for (int f = 0; f < 4; ++f)
#pragma unroll
    for (int r = 0; r < 4; ++r) {
      float v = m[f][r];
      v = fmaxf(v, __shfl_xor(v, 1, 64));
      v = fmaxf(v, __shfl_xor(v, 2, 64));
      v = fmaxf(v, __shfl_xor(v, 4, 64));
      v = fmaxf(v, __shfl_xor(v, 8, 64));
      if (col == 0) {
        unsigned b = __float_as_uint(v);
        unsigned e = (b & 0x80000000u) ? ~b : (b | 0x80000000u);
        atomicMax(&g_topu[tokBase + f * 16 + quad * 4 + r], e);
      }
    }
}

// GEMM pass 2 (r26, unchanged): same 16-split/8-stage skeleton; collect candidates.
__global__ __launch_bounds__(256) void k_mfma2() {
  __shared__ __align__(16) short smB[2][8192];
  int tid = threadIdx.x;
  int wave = tid >> 6, lane = tid & 63;
  int quad = lane >> 4, col = lane & 15;
  int tokGroup = blockIdx.x >> 4, split = blockIdx.x & 15;
  int tokBase = tokGroup * 256 + wave * 64;

  const short* za = g_znb + (size_t)(tokBase + col) * 64 + quad * 8;
  bf16x8 A0[4], A1[4];
#pragma unroll
  for (int f = 0; f < 4; ++f) {
    A0[f] = *(const bf16x8*)(za + f * 16 * 64);
    A1[f] = *(const bf16x8*)(za + f * 16 * 64 + 32);
  }
  float th[4][4];
#pragma unroll
  for (int f = 0; f < 4; ++f)
#pragma unroll
    for (int r = 0; r < 4; ++r) {
      unsigned u = g_topu[tokBase + f * 16 + quad * 4 + r];
      unsigned b = (u & 0x80000000u) ? (u & 0x7FFFFFFFu) : ~u;
      th[f][r] = __uint_as_float(b) - MARGIN_MFMA;
    }

  const char* gsplit = (const char*)(g_cnb + (size_t)split * 1024 * 64);
  int x = col & 7;
  int s0off = ((quad ^ x) << 3);
  int s1off = (((4 | quad) ^ x) << 3);
  int goff[4];
#pragma unroll
  for (int i = 0; i < 4; ++i) {
    int cidx = wave * 256 + i * 64 + lane;
    int row = cidx >> 3, sw = cidx & 7;
    goff[i] = row * 128 + ((sw ^ (row & 7)) << 4);
  }

#pragma unroll
  for (int i = 0; i < 4; ++i)
    __builtin_amdgcn_global_load_lds((const GLOBAL_AS void*)(gsplit + goff[i]),
                                     (LDS_AS void*)(&smB[0][wave * 2048 + i * 512]), 16, 0, 0);
  __syncthreads();

  int codeB = split * 1024 + col;
  int p = 0;
  for (int s = 0; s < 8; ++s) {
    if (s < 7) {
      const char* gb = gsplit + (size_t)(s + 1) * 16384;
#pragma unroll
      for (int i = 0; i < 4; ++i)
        __builtin_amdgcn_global_load_lds((const GLOBAL_AS void*)(gb + goff[i]),
                                         (LDS_AS void*)(&smB[p ^ 1][wave * 2048 + i * 512]),
                                         16, 0, 0);
    }
    const short* bufp = smB[p];
#pragma unroll
    for (int h = 0; h < 2; ++h) {
      bf16x8 B0[4], B1[4];
#pragma unroll
      for (int t = 0; t < 4; ++t) {
        const short* lb = bufp + ((h * 4 + t) * 16 + col) * 64;
        B0[t] = *(const bf16x8*)(lb + s0off);
        B1[t] = *(const bf16x8*)(lb + s1off);
      }
#pragma unroll
      for (int t = 0; t < 4; ++t) {
        int code = codeB + s * 128 + (h * 4 + t) * 16;
#pragma unroll
        for (int f = 0; f < 4; ++f) {
          f32x4 acc = {0.f, 0.f, 0.f, 0.f};
          acc = __builtin_amdgcn_mfma_f32_16x16x32_bf16(A0[f], B0[t], acc, 0, 0, 0);
          acc = __builtin_amdgcn_mfma_f32_16x16x32_bf16(A1[f], B1[t], acc, 0, 0, 0);
          float dmax = fmaxf(fmaxf(acc[0] - th[f][0], acc[1] - th[f][1]),
                             fmaxf(acc[2] - th[f][2], acc[3] - th[f][3]));
          if (dmax >= 0.f) {
#pragma unroll
            for (int r = 0; r < 4; ++r) {
              if (acc[r] >= th[f][r]) {
                int tok = tokBase + f * 16 + quad * 4 + r;
                int pos = atomicAdd(&g_candcnt[tok], 1);
                if (pos < CAP) g_cand[tok * CAP + pos] = code;
              }
            }
          }
        }
      }
    }
    __syncthreads();
    p ^= 1;
  }
}

// k_scan (r26, unchanged): worklist of cnt>=2 tokens; 1 atomic/block.
__global__ __launch_bounds__(256) void k_scan() {
  __shared__ int flags[256];
  __shared__ int sbase;
  int tid = threadIdx.x;
  int tok = blockIdx.x * 256 + tid;
  int flag = (g_candcnt[tok] >= 2) ? 1 : 0;
  flags[tid] = flag;
  __syncthreads();
  if (tid == 0) {
    int run = 0;
    for (int i = 0; i < 256; ++i) {
      int f = flags[i];
      flags[i] = run;  // exclusive prefix
      run += f;
    }
    sbase = atomicAdd(&g_wln, run);
  }
  __syncthreads();
  if (flag) g_wl[sbase + flags[tid]] = tok;
}

// k_arb (r24/r26, unchanged): 1024 blocks x 4 waves = 4096 waves stride the worklist.
__global__ __launch_bounds__(256) void k_arb(const float* __restrict__ z,
                                             const float* __restrict__ cb,
                                             const float* __restrict__ pw,
                                             const float* __restrict__ pb) {
  __shared__ double WT[64 * 65];  // WT[k*65+j] = W[j][k]
  __shared__ float cbl[4][64];
  int tid = threadIdx.x;
  int wave = tid >> 6, lane = tid & 63;
  for (int e = tid; e < 4096; e += 256) {
    int j = e >> 6, k = e & 63;
    WT[k * 65 + j] = (double)pw[e];
  }
  __syncthreads();

  int wln = g_wln;
  double bj = (double)pb[lane];
  int gwave = blockIdx.x * 4 + wave;

  for (int e = gwave; e < wln; e += 4096) {
    int tok = g_wl[e];
    int cnt = g_candcnt[tok];
    double zj = (double)z[(size_t)tok * 64 + lane];
    double best = -1.0e300;
    int bi = 0x7FFFFFFF;
    int lim = (cnt <= CAP) ? cnt : 0;
    for (int c = 0; c < lim; ++c) {
      int code = g_cand[tok * CAP + c];
      cbl[wave][lane] = cb[(size_t)code * 64 + lane];
      double s0 = 0.0, s1 = 0.0, s2 = 0.0, s3 = 0.0;
#pragma unroll
      for (int kk = 0; kk < 16; ++kk) {
        s0 = fma(WT[kk * 65 + lane], (double)cbl[wave][kk], s0);
        s1 = fma(WT[(kk + 16) * 65 + lane], (double)cbl[wave][kk + 16], s1);
        s2 = fma(WT[(kk + 32) * 65 + lane], (double)cbl[wave][kk + 32], s2);
        s3 = fma(WT[(kk + 48) * 65 + lane], (double)cbl[wave][kk + 48], s3);
      }
      double qc = ((s0 + s1) + (s2 + s3)) + bj;
      double s = zj * qc, n2 = qc * qc;
#pragma unroll
      for (int o = 32; o > 0; o >>= 1) {
        s += __shfl_xor(s, o, 64);
        n2 += __shfl_xor(n2, o, 64);
      }
      double key = s / fmax(sqrt(n2), 1e-12);
      if (key > best || (key == best && code < bi)) { best = key; bi = code; }
    }
    if (cnt > CAP) {  // correctness insurance; empirically never fires
      for (int code = 0; code < NCODES; ++code) {
        cbl[wave][lane] = cb[(size_t)code * 64 + lane];
        double s0 = 0.0, s1 = 0.0, s2 = 0.0, s3 = 0.0;
#pragma unroll
        for (int kk = 0; kk < 16; ++kk) {
          s0 = fma(WT[kk * 65 + lane], (double)cbl[wave][kk], s0);
          s1 = fma(WT[(kk + 16) * 65 + lane], (double)cbl[wave][kk + 16], s1);
          s2 = fma(WT[(kk + 32) * 65 + lane], (double)cbl[wave][kk + 32], s2);
          s3 = fma(WT[(kk + 48) * 65 + lane], (double)cbl[wave][kk + 48], s3);
        }
        double qc = ((s0 + s1) + (s2 + s3)) + bj;
        double s = zj * qc, n2 = qc * qc;
#pragma unroll
        for (int o = 32; o > 0; o >>= 1) {
          s += __shfl_xor(s, o, 64);
          n2 += __shfl_xor(n2, o, 64);
        }
        double key = s / fmax(sqrt(n2), 1e-12);
        if (key > best || (key == best && code < bi)) { best = key; bi = code; }
      }
    }
    if (lane == 0) g_cand[tok * CAP] = bi;
  }
}

// k_out (r29): 2048 blocks x 4 waves, wave owns 2 tokens (was 512 blocks x 8 tok/wave,
// 2 blocks/CU latency-bound). 8 blocks/CU, idx prefetched for both tokens; traffic
// ~12MB -> BW floor ~2µs. Loss partial per block (fixed-order final sum in k_loss).
__global__ __launch_bounds__(256) void k_out(const float* __restrict__ z,
                                             float* __restrict__ out0,
                                             float* __restrict__ out2) {
  __shared__ float ws[4];
  int tid = threadIdx.x;
  int wave = tid >> 6, lane = tid & 63;
  int base = blockIdx.x * 8 + wave * 2;
  int i0 = g_cand[(size_t)base * CAP];
  int i1 = g_cand[(size_t)(base + 1) * CAP];
  float q0 = g_qcb[(size_t)i0 * 64 + lane];
  float z0 = z[(size_t)base * 64 + lane];
  float q1 = g_qcb[(size_t)i1 * 64 + lane];
  float z1 = z[(size_t)(base + 1) * 64 + lane];
  float d0 = q0 - z0;
  float d1 = q1 - z1;
  out0[(size_t)base * 64 + lane] = z0 + d0;        // z + (q - z), ref op order
  out0[(size_t)(base + 1) * 64 + lane] = z1 + d1;
  if (lane == 0) {
    out2[base] = (float)i0;
    out2[base + 1] = (float)i1;
  }
  float lsum = fmaf(d0, d0, d1 * d1);
  float tot = wave_sum64(lsum);
  if (lane == 0) ws[wave] = tot;
  __syncthreads();
  if (tid == 0) g_partial[blockIdx.x] = ((ws[0] + ws[1]) + (ws[2] + ws[3]));
}

// k_loss: one wave sums the 2048 partials in fixed order -> out1.
__global__ void k_loss(float* __restrict__ out1) {
  int lane = threadIdx.x;
  float s = 0.f;
#pragma unroll
  for (int i = 0; i < 32; ++i) s += g_partial[lane + 64 * i];
  s = wave_sum64(s);
  if (lane == 0) out1[0] = 1.25f * s / 1048576.0f;  // commitment == codebook numerically
}

extern "C" void kernel_launch(void* const* d_in, const int* in_sizes, int n_in,
                              void* d_out, int out_size, void* d_ws, size_t ws_size,
                              hipStream_t stream) {
  const float* z = (const float*)d_in[0];
  const float* cb = (const float*)d_in[1];
  const float* pw = (const float*)d_in[2];
  const float* pb = (const float*)d_in[3];
  // d_in[4] (scale) unused: argmin invariant to positive scale

  float* out0 = (float*)d_out;
  float* out1 = out0 + (size_t)NTOK * DIM;
  float* out2 = out1 + 1;

  hipLaunchKernelGGL(k_prep, dim3(1280), dim3(256), 0, stream, cb, pw, pb, z);
  hipLaunchKernelGGL(k_mfma1, dim3(1024), dim3(256), 0, stream);
  hipLaunchKernelGGL(k_mfma2, dim3(1024), dim3(256), 0, stream);
  hipLaunchKernelGGL(k_scan, dim3(64), dim3(256), 0, stream);
  hipLaunchKernelGGL(k_arb, dim3(1024), dim3(256), 0, stream, z, cb, pw, pb);
  hipLaunchKernelGGL(k_out, dim3(2048), dim3(256), 0, stream, z, out0, out2);
  hipLaunchKernelGGL(k_loss, dim3(1), dim3(64), 0, stream, out1);
}